// Round 3
// baseline (2000.845 us; speedup 1.0000x reference)
//
#include <hip/hip_runtime.h>
#include <math.h>

#define HIDDEN   1024
#define HEADS    16
#define HEAD_DIM 64
#define BATCH    4
#define SEQ      4096
#define M_TOTAL  (BATCH * SEQ)          // 16384
#define FFT_N    4096
#define PI2      6.28318530717958647692f

// ---------------------------------------------------------------------------
// GEMM A: fused QKV projection, stores C^T:
//   qkvt[p][n][m] = sum_k x[m][k] * W_p[n][k] + b_p[n]
//   n in [0,1024) = h*64+d, m in [0,16384) = b*4096+s
// 128x128 tile, BK=16, 256 threads, 8x8 microkernel.
// ---------------------------------------------------------------------------
__global__ __launch_bounds__(256) void gemm_qkv_kernel(
    const float* __restrict__ x,
    const float* __restrict__ Wq, const float* __restrict__ Wk,
    const float* __restrict__ Wv,
    const float* __restrict__ bq, const float* __restrict__ bk,
    const float* __restrict__ bv,
    float* __restrict__ qkvt)
{
    __shared__ float As[16][128];   // k-major
    __shared__ float Bs[16][128];   // k-major

    const int tid = threadIdx.x;
    const int m0  = blockIdx.x * 128;
    const int p   = blockIdx.y >> 3;          // 0=q 1=k 2=v
    const int n0  = (blockIdx.y & 7) * 128;

    const float* W    = (p == 0) ? Wq : (p == 1 ? Wk : Wv);
    const float* bias = (p == 0) ? bq : (p == 1 ? bk : bv);
    float* ct = qkvt + (size_t)p * HIDDEN * M_TOTAL;

    const int tm = tid & 15;   // m sub-tile
    const int tn = tid >> 4;   // n sub-tile

    float acc[8][8];
    #pragma unroll
    for (int i = 0; i < 8; ++i)
        #pragma unroll
        for (int j = 0; j < 8; ++j) acc[i][j] = 0.f;

    for (int k0 = 0; k0 < HIDDEN; k0 += 16) {
        // load tiles (transposed into k-major LDS)
        #pragma unroll
        for (int l = 0; l < 2; ++l) {
            const int f   = tid + l * 256;      // [0,512)
            const int row = f >> 2;             // [0,128)
            const int kc  = (f & 3) << 2;       // 0,4,8,12
            float4 av = *(const float4*)(x + (size_t)(m0 + row) * HIDDEN + k0 + kc);
            As[kc + 0][row] = av.x; As[kc + 1][row] = av.y;
            As[kc + 2][row] = av.z; As[kc + 3][row] = av.w;
            float4 bv4 = *(const float4*)(W + (size_t)(n0 + row) * HIDDEN + k0 + kc);
            Bs[kc + 0][row] = bv4.x; Bs[kc + 1][row] = bv4.y;
            Bs[kc + 2][row] = bv4.z; Bs[kc + 3][row] = bv4.w;
        }
        __syncthreads();

        #pragma unroll
        for (int kk = 0; kk < 16; ++kk) {
            float a[8], b[8];
            *(float4*)&a[0] = *(const float4*)&As[kk][tm * 8];
            *(float4*)&a[4] = *(const float4*)&As[kk][tm * 8 + 4];
            *(float4*)&b[0] = *(const float4*)&Bs[kk][tn * 8];
            *(float4*)&b[4] = *(const float4*)&Bs[kk][tn * 8 + 4];
            #pragma unroll
            for (int i = 0; i < 8; ++i)
                #pragma unroll
                for (int j = 0; j < 8; ++j)
                    acc[i][j] = fmaf(a[i], b[j], acc[i][j]);
        }
        __syncthreads();
    }

    // epilogue: transposed store ct[n][m], contiguous in m
    #pragma unroll
    for (int j = 0; j < 8; ++j) {
        const int n = n0 + tn * 8 + j;
        const float bv = bias[n];
        float* dst = ct + (size_t)n * M_TOTAL + m0 + tm * 8;
        float4 v0 = { acc[0][j] + bv, acc[1][j] + bv, acc[2][j] + bv, acc[3][j] + bv };
        float4 v1 = { acc[4][j] + bv, acc[5][j] + bv, acc[6][j] + bv, acc[7][j] + bv };
        *(float4*)(dst + 0) = v0;
        *(float4*)(dst + 4) = v1;
    }
}

// ---------------------------------------------------------------------------
// FFT kernel: one block per (n, b) sequence.
// Radix-2 iterative DIT, in-place in LDS, bit-reversal permutation,
// twiddle table in LDS. z = fft(q + i*k) packs two real FFTs.
// ---------------------------------------------------------------------------
__device__ __forceinline__ void fft4096(float2* buf, const float2* tw, int tid)
{
    // bit-reversal permutation (12-bit)
    for (int i = tid; i < FFT_N; i += 256) {
        const int r = __brev(i) >> 20;
        if (i < r) {
            float2 a = buf[i], b = buf[r];
            buf[r] = a; buf[i] = b;
        }
    }
    __syncthreads();

    for (int stage = 0; stage < 12; ++stage) {
        const int half  = 1 << stage;
        const int tstep = 2048 >> stage;
        for (int j = tid; j < FFT_N / 2; j += 256) {
            const int pos  = j & (half - 1);
            const int base = (j >> stage) << (stage + 1);
            const int i0 = base + pos;
            const int i1 = i0 + half;
            const float2 w  = tw[pos * tstep];
            const float2 x0 = buf[i0];
            const float2 x1 = buf[i1];
            const float2 t = { w.x * x1.x - w.y * x1.y,
                               w.x * x1.y + w.y * x1.x };
            buf[i0] = { x0.x + t.x, x0.y + t.y };
            buf[i1] = { x0.x - t.x, x0.y - t.y };
        }
        __syncthreads();
    }
}

__global__ __launch_bounds__(256) void fft_attn_kernel(
    const float* __restrict__ qt, const float* __restrict__ kt,
    const float* __restrict__ vt, float* __restrict__ ot)
{
    __shared__ float2 bufA[FFT_N];
    __shared__ float2 bufB[FFT_N];
    __shared__ float2 tw[FFT_N / 2];

    const int tid = threadIdx.x;
    const int bid = blockIdx.x;          // [0, 4096)
    const int n   = bid >> 2;            // hidden index h*64+d
    const int b   = bid & 3;             // batch

    const size_t off = (size_t)n * M_TOTAL + (size_t)b * SEQ;
    const float* qrow = qt + off;
    const float* krow = kt + off;
    const float* vrow = vt + off;
    float*       orow = ot + off;

    // twiddle table: tw[j] = exp(-2*pi*i*j/N)
    for (int j = tid; j < FFT_N / 2; j += 256) {
        float s, c;
        __sincosf(-PI2 * (float)j / (float)FFT_N, &s, &c);
        tw[j] = { c, s };
    }
    // load q + i*k and v
    for (int s = tid; s < FFT_N; s += 256) {
        bufA[s] = { qrow[s], krow[s] };
        bufB[s] = { vrow[s], 0.f };
    }
    __syncthreads();

    fft4096(bufA, tw, tid);   // Z = Q + i*K
    fft4096(bufB, tw, tid);   // V

    // pointwise: F = Q * conj(K) * V ; store conj(F) for inverse-via-forward
    for (int j = tid; j < FFT_N; j += 256) {
        const float2 Zj = bufA[j];
        const float2 Zn = bufA[(FFT_N - j) & (FFT_N - 1)];
        // Q = (Z[j] + conj(Z[N-j]))/2
        const float2 Q = { 0.5f * (Zj.x + Zn.x), 0.5f * (Zj.y - Zn.y) };
        // K = (Z[j] - conj(Z[N-j]))/(2i)
        const float2 K = { 0.5f * (Zj.y + Zn.y), -0.5f * (Zj.x - Zn.x) };
        // G = Q * conj(K)
        const float2 G = { Q.x * K.x + Q.y * K.y, Q.y * K.x - Q.x * K.y };
        const float2 V = bufB[j];
        // F = G * V
        const float2 F = { G.x * V.x - G.y * V.y, G.x * V.y + G.y * V.x };
        bufB[j] = { F.x, -F.y };          // conj for inverse trick
    }
    __syncthreads();

    fft4096(bufB, tw, tid);   // fft(conj(F)) ; ifft = conj(.)/N

    const float scale = (1.0f / (float)FFT_N) * 0.125f;  // 1/N * 1/sqrt(64)
    for (int s = tid; s < FFT_N; s += 256)
        orow[s] = bufB[s].x * scale;
}

// ---------------------------------------------------------------------------
// GEMM C: out[m][n] = sum_k ot[k][m] * Wo[n][k] + bo[n]
// A is k-major (ot), so A-tile loads are contiguous float4.
// ---------------------------------------------------------------------------
__global__ __launch_bounds__(256) void gemm_out_kernel(
    const float* __restrict__ ot, const float* __restrict__ Wo,
    const float* __restrict__ bo, float* __restrict__ out)
{
    __shared__ float As[16][128];   // k-major
    __shared__ float Bs[16][128];   // k-major

    const int tid = threadIdx.x;
    const int m0  = blockIdx.x * 128;
    const int n0  = blockIdx.y * 128;

    const int tm = tid & 15;
    const int tn = tid >> 4;

    float acc[8][8];
    #pragma unroll
    for (int i = 0; i < 8; ++i)
        #pragma unroll
        for (int j = 0; j < 8; ++j) acc[i][j] = 0.f;

    for (int k0 = 0; k0 < HIDDEN; k0 += 16) {
        #pragma unroll
        for (int l = 0; l < 2; ++l) {
            const int f  = tid + l * 256;       // [0,512)
            const int kk = f >> 5;              // [0,16)
            const int mc = (f & 31) << 2;       // [0,128)
            float4 av = *(const float4*)(ot + (size_t)(k0 + kk) * M_TOTAL + m0 + mc);
            *(float4*)&As[kk][mc] = av;
            const int row = f >> 2;             // [0,128)
            const int kc  = (f & 3) << 2;
            float4 bv4 = *(const float4*)(Wo + (size_t)(n0 + row) * HIDDEN + k0 + kc);
            Bs[kc + 0][row] = bv4.x; Bs[kc + 1][row] = bv4.y;
            Bs[kc + 2][row] = bv4.z; Bs[kc + 3][row] = bv4.w;
        }
        __syncthreads();

        #pragma unroll
        for (int kk = 0; kk < 16; ++kk) {
            float a[8], b[8];
            *(float4*)&a[0] = *(const float4*)&As[kk][tm * 8];
            *(float4*)&a[4] = *(const float4*)&As[kk][tm * 8 + 4];
            *(float4*)&b[0] = *(const float4*)&Bs[kk][tn * 8];
            *(float4*)&b[4] = *(const float4*)&Bs[kk][tn * 8 + 4];
            #pragma unroll
            for (int i = 0; i < 8; ++i)
                #pragma unroll
                for (int j = 0; j < 8; ++j)
                    acc[i][j] = fmaf(a[i], b[j], acc[i][j]);
        }
        __syncthreads();
    }

    #pragma unroll
    for (int i = 0; i < 8; ++i) {
        const int m = m0 + tm * 8 + i;
        float* dst = out + (size_t)m * HIDDEN + n0 + tn * 8;
        float4 v0 = { acc[i][0] + bo[n0 + tn * 8 + 0],
                      acc[i][1] + bo[n0 + tn * 8 + 1],
                      acc[i][2] + bo[n0 + tn * 8 + 2],
                      acc[i][3] + bo[n0 + tn * 8 + 3] };
        float4 v1 = { acc[i][4] + bo[n0 + tn * 8 + 4],
                      acc[i][5] + bo[n0 + tn * 8 + 5],
                      acc[i][6] + bo[n0 + tn * 8 + 6],
                      acc[i][7] + bo[n0 + tn * 8 + 7] };
        *(float4*)(dst + 0) = v0;
        *(float4*)(dst + 4) = v1;
    }
}

// ---------------------------------------------------------------------------
extern "C" void kernel_launch(void* const* d_in, const int* in_sizes, int n_in,
                              void* d_out, int out_size, void* d_ws, size_t ws_size,
                              hipStream_t stream)
{
    const float* x  = (const float*)d_in[0];
    const float* Wq = (const float*)d_in[1];
    const float* bq = (const float*)d_in[2];
    const float* Wk = (const float*)d_in[3];
    const float* bk = (const float*)d_in[4];
    const float* Wv = (const float*)d_in[5];
    const float* bv = (const float*)d_in[6];
    const float* Wo = (const float*)d_in[7];
    const float* bo = (const float*)d_in[8];
    float* out = (float*)d_out;

    float* qkvt = (float*)d_ws;                       // [3][1024][16384] fp32
    float* qt = qkvt;
    float* kt = qkvt + (size_t)HIDDEN * M_TOTAL;
    float* vt = qkvt + (size_t)2 * HIDDEN * M_TOTAL;
    float* ot = qt;   // FFT output aliases q region (safe: q consumed per-block first)

    // 1) QKV projections -> transposed layout
    gemm_qkv_kernel<<<dim3(M_TOTAL / 128, 24), 256, 0, stream>>>(
        x, Wq, Wk, Wv, bq, bk, bv, qkvt);

    // 2) per-sequence FFT attention
    fft_attn_kernel<<<dim3(HIDDEN * BATCH), 256, 0, stream>>>(qt, kt, vt, ot);

    // 3) output projection
    gemm_out_kernel<<<dim3(M_TOTAL / 128, HIDDEN / 128), 256, 0, stream>>>(
        ot, Wo, bo, out);
}

// Round 4
// 871.041 us; speedup vs baseline: 2.2971x; 2.2971x over previous
//
#include <hip/hip_runtime.h>
#include <math.h>

#define HIDDEN   1024
#define HEADS    16
#define HEAD_DIM 64
#define BATCH    4
#define SEQ      4096
#define M_TOTAL  (BATCH * SEQ)          // 16384
#define FFT_N    4096
#define PI2      6.28318530717958647692f

typedef short  s16x8 __attribute__((ext_vector_type(8)));   // 8 bf16 = 4 VGPR (MFMA A/B frag)
typedef float  f32x4 __attribute__((ext_vector_type(4)));   // MFMA C/D frag

// truncation split: x = hi + lo, both bf16 (hi = top 16 bits; lo = bf16(x - hi))
__device__ __forceinline__ void split1(float v, ushort& h, ushort& l) {
    unsigned u = __float_as_uint(v);
    h = (ushort)(u >> 16);
    float hif = __uint_as_float(u & 0xffff0000u);
    float lof = v - hif;
    l = (ushort)(__float_as_uint(lof) >> 16);
}

// ---------------------------------------------------------------------------
// GEMM A (MFMA): fused QKV projection, stores C^T:
//   ct[n][m] = sum_k W[n][k] * x[m][k] + bias[n]
// D[n][m] tile: A-frag = W (row n = lane%16, k contiguous),
//               B-frag = x (col m = lane%16, k contiguous).
// Split-bf16 3-product: Ah*Bh + Ah*Bl + Al*Bh. In-kernel split during staging.
// Block: 128n x 128m, 4 waves (each 32n x 128m), BK=32, chunk-XOR LDS swizzle.
// ---------------------------------------------------------------------------
__global__ __launch_bounds__(256) void gemm_qkv_mfma(
    const float* __restrict__ x,
    const float* __restrict__ Wq, const float* __restrict__ Wk,
    const float* __restrict__ Wv,
    const float* __restrict__ bq, const float* __restrict__ bk,
    const float* __restrict__ bv,
    float* __restrict__ qkvt)
{
    __shared__ ushort Ah[128][32], Al[128][32];   // W tile  [n][k] hi/lo (8 KB each)
    __shared__ ushort Bh[128][32], Bl[128][32];   // x tile  [m][k] hi/lo

    const int tid  = threadIdx.x;
    const int lane = tid & 63;
    const int w    = tid >> 6;
    const int m0   = blockIdx.x * 128;
    const int p    = blockIdx.y >> 3;            // 0=q 1=k 2=v
    const int n0   = (blockIdx.y & 7) * 128;

    const float* __restrict__ W    = (p == 0) ? Wq : (p == 1 ? Wk : Wv);
    const float* __restrict__ bias = (p == 0) ? bq : (p == 1 ? bk : bv);
    float* __restrict__ ct = qkvt + (size_t)p * HIDDEN * M_TOTAL;

    const int fr = lane & 15;     // frag row/col within 16-tile
    const int fc = lane >> 4;     // frag k-chunk 0..3
    const int cc = (fc ^ (fr & 3)) * 8;   // swizzled LDS element-column (constant: tiles are 16-row aligned)

    f32x4 acc[2][8];
    #pragma unroll
    for (int i = 0; i < 2; ++i)
        #pragma unroll
        for (int j = 0; j < 8; ++j)
            acc[i][j] = (f32x4){0.f, 0.f, 0.f, 0.f};

    for (int ks = 0; ks < HIDDEN / 32; ++ks) {
        const int k0 = ks * 32;
        __syncthreads();
        // ---- stage: 512 16B-slots per array pair; slot s = (row=s>>2, chunk=s&3)
        #pragma unroll
        for (int t = 0; t < 2; ++t) {
            const int s   = tid + t * 256;
            const int row = s >> 2;
            const int ch  = s & 3;
            const int cs  = (ch ^ (row & 3)) * 8;   // swizzled write column
            {   // A: W rows n0+row
                const float* g = W + (size_t)(n0 + row) * HIDDEN + k0 + ch * 8;
                float4 v0 = *(const float4*)g;
                float4 v1 = *(const float4*)(g + 4);
                const float vv[8] = {v0.x, v0.y, v0.z, v0.w, v1.x, v1.y, v1.z, v1.w};
                s16x8 hv, lv;
                #pragma unroll
                for (int e = 0; e < 8; ++e) {
                    ushort h, l; split1(vv[e], h, l);
                    hv[e] = (short)h; lv[e] = (short)l;
                }
                *(s16x8*)&Ah[row][cs] = hv;
                *(s16x8*)&Al[row][cs] = lv;
            }
            {   // B: x rows m0+row
                const float* g = x + (size_t)(m0 + row) * HIDDEN + k0 + ch * 8;
                float4 v0 = *(const float4*)g;
                float4 v1 = *(const float4*)(g + 4);
                const float vv[8] = {v0.x, v0.y, v0.z, v0.w, v1.x, v1.y, v1.z, v1.w};
                s16x8 hv, lv;
                #pragma unroll
                for (int e = 0; e < 8; ++e) {
                    ushort h, l; split1(vv[e], h, l);
                    hv[e] = (short)h; lv[e] = (short)l;
                }
                *(s16x8*)&Bh[row][cs] = hv;
                *(s16x8*)&Bl[row][cs] = lv;
            }
        }
        __syncthreads();
        // ---- compute: wave w owns n-local rows [w*32, w*32+32)
        s16x8 a_h[2], a_l[2];
        #pragma unroll
        for (int i = 0; i < 2; ++i) {
            const int R = w * 32 + i * 16 + fr;
            a_h[i] = *(const s16x8*)&Ah[R][cc];
            a_l[i] = *(const s16x8*)&Al[R][cc];
        }
        #pragma unroll
        for (int j = 0; j < 8; ++j) {
            const int R = j * 16 + fr;
            const s16x8 b_h = *(const s16x8*)&Bh[R][cc];
            const s16x8 b_l = *(const s16x8*)&Bl[R][cc];
            #pragma unroll
            for (int i = 0; i < 2; ++i) {
                acc[i][j] = __builtin_amdgcn_mfma_f32_16x16x32_bf16(a_h[i], b_h, acc[i][j], 0, 0, 0);
                acc[i][j] = __builtin_amdgcn_mfma_f32_16x16x32_bf16(a_h[i], b_l, acc[i][j], 0, 0, 0);
                acc[i][j] = __builtin_amdgcn_mfma_f32_16x16x32_bf16(a_l[i], b_h, acc[i][j], 0, 0, 0);
            }
        }
    }

    // ---- epilogue: D row n = (lane>>4)*4 + r, col m = lane&15
    const int rq = lane >> 4;
    #pragma unroll
    for (int i = 0; i < 2; ++i) {
        #pragma unroll
        for (int r = 0; r < 4; ++r) {
            const int n = n0 + w * 32 + i * 16 + rq * 4 + r;
            const float bv = bias[n];
            float* dst = ct + (size_t)n * M_TOTAL + m0;
            #pragma unroll
            for (int j = 0; j < 8; ++j)
                dst[j * 16 + fr] = acc[i][j][r] + bv;
        }
    }
}

// ---------------------------------------------------------------------------
// FFT kernel (UNCHANGED from validated round-3 baseline)
// ---------------------------------------------------------------------------
__device__ __forceinline__ void fft4096(float2* buf, const float2* tw, int tid)
{
    for (int i = tid; i < FFT_N; i += 256) {
        const int r = __brev(i) >> 20;
        if (i < r) {
            float2 a = buf[i], b = buf[r];
            buf[r] = a; buf[i] = b;
        }
    }
    __syncthreads();

    for (int stage = 0; stage < 12; ++stage) {
        const int half  = 1 << stage;
        const int tstep = 2048 >> stage;
        for (int j = tid; j < FFT_N / 2; j += 256) {
            const int pos  = j & (half - 1);
            const int base = (j >> stage) << (stage + 1);
            const int i0 = base + pos;
            const int i1 = i0 + half;
            const float2 w  = tw[pos * tstep];
            const float2 x0 = buf[i0];
            const float2 x1 = buf[i1];
            const float2 t = { w.x * x1.x - w.y * x1.y,
                               w.x * x1.y + w.y * x1.x };
            buf[i0] = { x0.x + t.x, x0.y + t.y };
            buf[i1] = { x0.x - t.x, x0.y - t.y };
        }
        __syncthreads();
    }
}

__global__ __launch_bounds__(256) void fft_attn_kernel(
    const float* __restrict__ qt, const float* __restrict__ kt,
    const float* __restrict__ vt, float* __restrict__ ot)
{
    __shared__ float2 bufA[FFT_N];
    __shared__ float2 bufB[FFT_N];
    __shared__ float2 tw[FFT_N / 2];

    const int tid = threadIdx.x;
    const int bid = blockIdx.x;
    const int n   = bid >> 2;
    const int b   = bid & 3;

    const size_t off = (size_t)n * M_TOTAL + (size_t)b * SEQ;
    const float* qrow = qt + off;
    const float* krow = kt + off;
    const float* vrow = vt + off;
    float*       orow = ot + off;

    for (int j = tid; j < FFT_N / 2; j += 256) {
        float s, c;
        __sincosf(-PI2 * (float)j / (float)FFT_N, &s, &c);
        tw[j] = { c, s };
    }
    for (int s = tid; s < FFT_N; s += 256) {
        bufA[s] = { qrow[s], krow[s] };
        bufB[s] = { vrow[s], 0.f };
    }
    __syncthreads();

    fft4096(bufA, tw, tid);
    fft4096(bufB, tw, tid);

    for (int j = tid; j < FFT_N; j += 256) {
        const float2 Zj = bufA[j];
        const float2 Zn = bufA[(FFT_N - j) & (FFT_N - 1)];
        const float2 Q = { 0.5f * (Zj.x + Zn.x), 0.5f * (Zj.y - Zn.y) };
        const float2 K = { 0.5f * (Zj.y + Zn.y), -0.5f * (Zj.x - Zn.x) };
        const float2 G = { Q.x * K.x + Q.y * K.y, Q.y * K.x - Q.x * K.y };
        const float2 V = bufB[j];
        const float2 F = { G.x * V.x - G.y * V.y, G.x * V.y + G.y * V.x };
        bufB[j] = { F.x, -F.y };
    }
    __syncthreads();

    fft4096(bufB, tw, tid);

    const float scale = (1.0f / (float)FFT_N) * 0.125f;
    for (int s = tid; s < FFT_N; s += 256)
        orow[s] = bufB[s].x * scale;
}

// ---------------------------------------------------------------------------
// Transpose + split: ot fp32 [n=1024][m=16384]  ->  oth/otl bf16 [m][k=n]
// 64x64 tiles via LDS.
// ---------------------------------------------------------------------------
__global__ __launch_bounds__(256) void transpose_split_kernel(
    const float* __restrict__ ot, ushort* __restrict__ oth,
    ushort* __restrict__ otl)
{
    __shared__ float tile[64][65];
    const int tid = threadIdx.x;
    const int m0  = blockIdx.x * 64;
    const int n0  = blockIdx.y * 64;
    const int r   = tid >> 4;     // 0..15
    const int c   = tid & 15;

    #pragma unroll
    for (int rr = 0; rr < 4; ++rr) {
        const int nl = r + rr * 16;
        float4 v = *(const float4*)(ot + (size_t)(n0 + nl) * M_TOTAL + m0 + c * 4);
        tile[nl][c * 4 + 0] = v.x; tile[nl][c * 4 + 1] = v.y;
        tile[nl][c * 4 + 2] = v.z; tile[nl][c * 4 + 3] = v.w;
    }
    __syncthreads();
    #pragma unroll
    for (int rr = 0; rr < 4; ++rr) {
        const int ml = r + rr * 16;
        ushort4 h, l;
        split1(tile[c * 4 + 0][ml], h.x, l.x);
        split1(tile[c * 4 + 1][ml], h.y, l.y);
        split1(tile[c * 4 + 2][ml], h.z, l.z);
        split1(tile[c * 4 + 3][ml], h.w, l.w);
        *(ushort4*)(oth + (size_t)(m0 + ml) * HIDDEN + n0 + c * 4) = h;
        *(ushort4*)(otl + (size_t)(m0 + ml) * HIDDEN + n0 + c * 4) = l;
    }
}

// ---------------------------------------------------------------------------
// GEMM C (MFMA): out[m][n] = sum_k ot^T[m][k] * Wo[n][k] + bo[n]
// D[m][n] tile: A-frag = ot^T (bf16 planes, k contiguous), B-frag = Wo (split in-kernel).
// ---------------------------------------------------------------------------
__global__ __launch_bounds__(256) void gemm_out_mfma(
    const ushort* __restrict__ oth, const ushort* __restrict__ otl,
    const float* __restrict__ Wo, const float* __restrict__ bo,
    float* __restrict__ out)
{
    __shared__ ushort Ah[128][32], Al[128][32];   // ot^T tile [m][k]
    __shared__ ushort Bh[128][32], Bl[128][32];   // Wo  tile [n][k]

    const int tid  = threadIdx.x;
    const int lane = tid & 63;
    const int w    = tid >> 6;
    const int m0   = blockIdx.x * 128;
    const int n0   = blockIdx.y * 128;

    const int fr = lane & 15;
    const int fc = lane >> 4;
    const int cc = (fc ^ (fr & 3)) * 8;

    f32x4 acc[2][8];
    #pragma unroll
    for (int i = 0; i < 2; ++i)
        #pragma unroll
        for (int j = 0; j < 8; ++j)
            acc[i][j] = (f32x4){0.f, 0.f, 0.f, 0.f};

    for (int ks = 0; ks < HIDDEN / 32; ++ks) {
        const int k0 = ks * 32;
        __syncthreads();
        #pragma unroll
        for (int t = 0; t < 2; ++t) {
            const int s   = tid + t * 256;
            const int row = s >> 2;
            const int ch  = s & 3;
            const int cs  = (ch ^ (row & 3)) * 8;
            {   // A: bf16 planes, direct 16B copies
                const size_t g = (size_t)(m0 + row) * HIDDEN + k0 + ch * 8;
                *(s16x8*)&Ah[row][cs] = *(const s16x8*)(oth + g);
                *(s16x8*)&Al[row][cs] = *(const s16x8*)(otl + g);
            }
            {   // B: Wo fp32, split
                const float* g = Wo + (size_t)(n0 + row) * HIDDEN + k0 + ch * 8;
                float4 v0 = *(const float4*)g;
                float4 v1 = *(const float4*)(g + 4);
                const float vv[8] = {v0.x, v0.y, v0.z, v0.w, v1.x, v1.y, v1.z, v1.w};
                s16x8 hv, lv;
                #pragma unroll
                for (int e = 0; e < 8; ++e) {
                    ushort h, l; split1(vv[e], h, l);
                    hv[e] = (short)h; lv[e] = (short)l;
                }
                *(s16x8*)&Bh[row][cs] = hv;
                *(s16x8*)&Bl[row][cs] = lv;
            }
        }
        __syncthreads();
        s16x8 a_h[2], a_l[2];
        #pragma unroll
        for (int i = 0; i < 2; ++i) {
            const int R = w * 32 + i * 16 + fr;
            a_h[i] = *(const s16x8*)&Ah[R][cc];
            a_l[i] = *(const s16x8*)&Al[R][cc];
        }
        #pragma unroll
        for (int j = 0; j < 8; ++j) {
            const int R = j * 16 + fr;
            const s16x8 b_h = *(const s16x8*)&Bh[R][cc];
            const s16x8 b_l = *(const s16x8*)&Bl[R][cc];
            #pragma unroll
            for (int i = 0; i < 2; ++i) {
                acc[i][j] = __builtin_amdgcn_mfma_f32_16x16x32_bf16(a_h[i], b_h, acc[i][j], 0, 0, 0);
                acc[i][j] = __builtin_amdgcn_mfma_f32_16x16x32_bf16(a_h[i], b_l, acc[i][j], 0, 0, 0);
                acc[i][j] = __builtin_amdgcn_mfma_f32_16x16x32_bf16(a_l[i], b_h, acc[i][j], 0, 0, 0);
            }
        }
    }

    // epilogue: D row m = (lane>>4)*4 + r, col n = lane&15
    const int rq = lane >> 4;
    float bo_v[8];
    #pragma unroll
    for (int j = 0; j < 8; ++j) bo_v[j] = bo[n0 + j * 16 + fr];
    #pragma unroll
    for (int i = 0; i < 2; ++i) {
        #pragma unroll
        for (int r = 0; r < 4; ++r) {
            const int m = m0 + w * 32 + i * 16 + rq * 4 + r;
            float* dst = out + (size_t)m * HIDDEN + n0;
            #pragma unroll
            for (int j = 0; j < 8; ++j)
                dst[j * 16 + fr] = acc[i][j][r] + bo_v[j];
        }
    }
}

// ---------------------------------------------------------------------------
extern "C" void kernel_launch(void* const* d_in, const int* in_sizes, int n_in,
                              void* d_out, int out_size, void* d_ws, size_t ws_size,
                              hipStream_t stream)
{
    const float* x  = (const float*)d_in[0];
    const float* Wq = (const float*)d_in[1];
    const float* bq = (const float*)d_in[2];
    const float* Wk = (const float*)d_in[3];
    const float* bk = (const float*)d_in[4];
    const float* Wv = (const float*)d_in[5];
    const float* bv = (const float*)d_in[6];
    const float* Wo = (const float*)d_in[7];
    const float* bo = (const float*)d_in[8];
    float* out = (float*)d_out;

    const size_t plane = (size_t)HIDDEN * M_TOTAL;   // 16.7M floats = 64 MB
    float* qt = (float*)d_ws;
    float* kt = qt + plane;
    float* vt = qt + 2 * plane;
    float* ot = qt;                    // FFT output aliases q plane
    ushort* oth = (ushort*)kt;         // transposed bf16 hi plane (32 MB into dead k plane)
    ushort* otl = (ushort*)vt;         // lo plane (into dead v plane)

    // 1) QKV projections (MFMA, split-bf16) -> ct[n][m] fp32
    gemm_qkv_mfma<<<dim3(M_TOTAL / 128, 24), 256, 0, stream>>>(
        x, Wq, Wk, Wv, bq, bk, bv, qt);

    // 2) per-sequence FFT attention (fp32, unchanged)
    fft_attn_kernel<<<dim3(HIDDEN * BATCH), 256, 0, stream>>>(qt, kt, vt, ot);

    // 3) transpose + bf16 split: ot[n][m] -> oth/otl [m][k]
    transpose_split_kernel<<<dim3(M_TOTAL / 64, HIDDEN / 64), 256, 0, stream>>>(
        ot, oth, otl);

    // 4) output projection (MFMA, split-bf16) -> out[m][n]
    gemm_out_mfma<<<dim3(M_TOTAL / 128, HIDDEN / 128), 256, 0, stream>>>(
        oth, otl, Wo, bo, out);
}

// Round 5
// 598.338 us; speedup vs baseline: 3.3440x; 1.4558x over previous
//
#include <hip/hip_runtime.h>
#include <math.h>

#define HIDDEN   1024
#define HEADS    16
#define HEAD_DIM 64
#define BATCH    4
#define SEQ      4096
#define M_TOTAL  (BATCH * SEQ)          // 16384
#define FFT_N    4096
#define PI2      6.28318530717958647692f

typedef short  s16x8 __attribute__((ext_vector_type(8)));   // 8 bf16 = 4 VGPR (MFMA A/B frag)
typedef float  f32x4 __attribute__((ext_vector_type(4)));   // MFMA C/D frag

// truncation split: x = hi + lo, both bf16 (hi = top 16 bits; lo = bf16(x - hi))
__device__ __forceinline__ void split1(float v, ushort& h, ushort& l) {
    unsigned u = __float_as_uint(v);
    h = (ushort)(u >> 16);
    float hif = __uint_as_float(u & 0xffff0000u);
    float lof = v - hif;
    l = (ushort)(__float_as_uint(lof) >> 16);
}

// ---------------------------------------------------------------------------
// GEMM A (MFMA): fused QKV projection, stores C^T  (UNCHANGED, validated r4)
// ---------------------------------------------------------------------------
__global__ __launch_bounds__(256) void gemm_qkv_mfma(
    const float* __restrict__ x,
    const float* __restrict__ Wq, const float* __restrict__ Wk,
    const float* __restrict__ Wv,
    const float* __restrict__ bq, const float* __restrict__ bk,
    const float* __restrict__ bv,
    float* __restrict__ qkvt)
{
    __shared__ ushort Ah[128][32], Al[128][32];
    __shared__ ushort Bh[128][32], Bl[128][32];

    const int tid  = threadIdx.x;
    const int lane = tid & 63;
    const int w    = tid >> 6;
    const int m0   = blockIdx.x * 128;
    const int p    = blockIdx.y >> 3;
    const int n0   = (blockIdx.y & 7) * 128;

    const float* __restrict__ W    = (p == 0) ? Wq : (p == 1 ? Wk : Wv);
    const float* __restrict__ bias = (p == 0) ? bq : (p == 1 ? bk : bv);
    float* __restrict__ ct = qkvt + (size_t)p * HIDDEN * M_TOTAL;

    const int fr = lane & 15;
    const int fc = lane >> 4;
    const int cc = (fc ^ (fr & 3)) * 8;

    f32x4 acc[2][8];
    #pragma unroll
    for (int i = 0; i < 2; ++i)
        #pragma unroll
        for (int j = 0; j < 8; ++j)
            acc[i][j] = (f32x4){0.f, 0.f, 0.f, 0.f};

    for (int ks = 0; ks < HIDDEN / 32; ++ks) {
        const int k0 = ks * 32;
        __syncthreads();
        #pragma unroll
        for (int t = 0; t < 2; ++t) {
            const int s   = tid + t * 256;
            const int row = s >> 2;
            const int ch  = s & 3;
            const int cs  = (ch ^ (row & 3)) * 8;
            {
                const float* g = W + (size_t)(n0 + row) * HIDDEN + k0 + ch * 8;
                float4 v0 = *(const float4*)g;
                float4 v1 = *(const float4*)(g + 4);
                const float vv[8] = {v0.x, v0.y, v0.z, v0.w, v1.x, v1.y, v1.z, v1.w};
                s16x8 hv, lv;
                #pragma unroll
                for (int e = 0; e < 8; ++e) {
                    ushort h, l; split1(vv[e], h, l);
                    hv[e] = (short)h; lv[e] = (short)l;
                }
                *(s16x8*)&Ah[row][cs] = hv;
                *(s16x8*)&Al[row][cs] = lv;
            }
            {
                const float* g = x + (size_t)(m0 + row) * HIDDEN + k0 + ch * 8;
                float4 v0 = *(const float4*)g;
                float4 v1 = *(const float4*)(g + 4);
                const float vv[8] = {v0.x, v0.y, v0.z, v0.w, v1.x, v1.y, v1.z, v1.w};
                s16x8 hv, lv;
                #pragma unroll
                for (int e = 0; e < 8; ++e) {
                    ushort h, l; split1(vv[e], h, l);
                    hv[e] = (short)h; lv[e] = (short)l;
                }
                *(s16x8*)&Bh[row][cs] = hv;
                *(s16x8*)&Bl[row][cs] = lv;
            }
        }
        __syncthreads();
        s16x8 a_h[2], a_l[2];
        #pragma unroll
        for (int i = 0; i < 2; ++i) {
            const int R = w * 32 + i * 16 + fr;
            a_h[i] = *(const s16x8*)&Ah[R][cc];
            a_l[i] = *(const s16x8*)&Al[R][cc];
        }
        #pragma unroll
        for (int j = 0; j < 8; ++j) {
            const int R = j * 16 + fr;
            const s16x8 b_h = *(const s16x8*)&Bh[R][cc];
            const s16x8 b_l = *(const s16x8*)&Bl[R][cc];
            #pragma unroll
            for (int i = 0; i < 2; ++i) {
                acc[i][j] = __builtin_amdgcn_mfma_f32_16x16x32_bf16(a_h[i], b_h, acc[i][j], 0, 0, 0);
                acc[i][j] = __builtin_amdgcn_mfma_f32_16x16x32_bf16(a_h[i], b_l, acc[i][j], 0, 0, 0);
                acc[i][j] = __builtin_amdgcn_mfma_f32_16x16x32_bf16(a_l[i], b_h, acc[i][j], 0, 0, 0);
            }
        }
    }

    const int rq = lane >> 4;
    #pragma unroll
    for (int i = 0; i < 2; ++i) {
        #pragma unroll
        for (int r = 0; r < 4; ++r) {
            const int n = n0 + w * 32 + i * 16 + rq * 4 + r;
            const float bv = bias[n];
            float* dst = ct + (size_t)n * M_TOTAL + m0;
            #pragma unroll
            for (int j = 0; j < 8; ++j)
                dst[j * 16 + fr] = acc[i][j][r] + bv;
        }
    }
}

// ---------------------------------------------------------------------------
// Radix-16 FFT machinery. 4096 = 16^3; forward DIF -> digit-reversed order;
// pointwise in digit-reversed positions; inverse DIT -> natural order.
// ---------------------------------------------------------------------------
__device__ __forceinline__ float2 cmul(float2 a, float2 b) {
    return {a.x*b.x - a.y*b.y, a.x*b.y + a.y*b.x};
}

// LDS index swizzle: XOR low hex digit with middle digit -> all three stage
// access patterns (stride-256, stride-16, contiguous-16) are bank-clean.
__device__ __forceinline__ int phys(int p) { return p ^ ((p >> 4) & 15); }

// 16-point DFT in registers. DIR=-1 forward (W=e^{-2pi i/16}), +1 inverse.
template<int DIR>
__device__ __forceinline__ void dft16(const float2* x, float2* X) {
    float2 t[16];
    #pragma unroll
    for (int n0 = 0; n0 < 4; ++n0) {
        float2 a = x[n0], b = x[n0+4], c = x[n0+8], d = x[n0+12];
        float2 s0 = {a.x+c.x, a.y+c.y}, s1 = {a.x-c.x, a.y-c.y};
        float2 s2 = {b.x+d.x, b.y+d.y}, s3 = {b.x-d.x, b.y-d.y};
        t[n0*4+0] = {s0.x+s2.x, s0.y+s2.y};
        t[n0*4+2] = {s0.x-s2.x, s0.y-s2.y};
        if (DIR < 0) {
            t[n0*4+1] = {s1.x+s3.y, s1.y-s3.x};
            t[n0*4+3] = {s1.x-s3.y, s1.y+s3.x};
        } else {
            t[n0*4+1] = {s1.x-s3.y, s1.y+s3.x};
            t[n0*4+3] = {s1.x+s3.y, s1.y-s3.x};
        }
    }
    const float C1 = 0.92387953251128674f;
    const float S1_ = 0.38268343236508978f;
    const float R2 = 0.70710678118654752f;
    #define TW(idx, cc_, ss_) t[idx] = cmul(t[idx], (float2){cc_, DIR*(ss_)})
    TW(1*4+1, C1, S1_);   TW(1*4+2, R2, R2);    TW(1*4+3, S1_, C1);
    TW(2*4+1, R2, R2);    TW(2*4+2, 0.f, 1.f);  TW(2*4+3, -R2, R2);
    TW(3*4+1, S1_, C1);   TW(3*4+2, -R2, R2);   TW(3*4+3, -C1, -S1_);
    #undef TW
    #pragma unroll
    for (int k0 = 0; k0 < 4; ++k0) {
        float2 a = t[0+k0], b = t[4+k0], c = t[8+k0], d = t[12+k0];
        float2 s0 = {a.x+c.x, a.y+c.y}, s1 = {a.x-c.x, a.y-c.y};
        float2 s2 = {b.x+d.x, b.y+d.y}, s3 = {b.x-d.x, b.y-d.y};
        X[k0+0]  = {s0.x+s2.x, s0.y+s2.y};
        X[k0+8]  = {s0.x-s2.x, s0.y-s2.y};
        if (DIR < 0) {
            X[k0+4]  = {s1.x+s3.y, s1.y-s3.x};
            X[k0+12] = {s1.x-s3.y, s1.y+s3.x};
        } else {
            X[k0+4]  = {s1.x-s3.y, s1.y+s3.x};
            X[k0+12] = {s1.x+s3.y, s1.y-s3.x};
        }
    }
}

// y[u] *= e^{i*ang*u}, u=0..15 (incremental complex powers; 1 sincos)
__device__ __forceinline__ void twiddle_apply(float2* y, float ang) {
    float s, c;
    __sincosf(ang, &s, &c);
    const float2 base = {c, s};
    float2 w = base;
    #pragma unroll
    for (int u = 1; u < 16; ++u) {
        y[u] = cmul(y[u], w);
        w = cmul(w, base);
    }
}

__global__ __launch_bounds__(256) void fft_attn_kernel(
    const float* __restrict__ qt, const float* __restrict__ kt,
    const float* __restrict__ vt, float* __restrict__ ot)
{
    __shared__ float2 bufA[FFT_N];   // Z = fft(q + i k), digit-reversed
    __shared__ float2 bufB[FFT_N];   // V spectrum, then F, then inverse ws

    const int tid = threadIdx.x;
    const int bid = blockIdx.x;          // [0, 4096)
    const int n   = bid >> 2;
    const int b   = bid & 3;

    const size_t off = (size_t)n * M_TOTAL + (size_t)b * SEQ;
    const float* qrow = qt + off;
    const float* krow = kt + off;
    const float* vrow = vt + off;
    float*       orow = ot + off;

    // ---- forward stage 1 (stride 256), inputs straight from global
    {
        const int q = tid;
        float2 xA[16], xB[16], yA[16], yB[16];
        #pragma unroll
        for (int r = 0; r < 16; ++r) {
            xA[r] = { qrow[q + 256*r], krow[q + 256*r] };
            xB[r] = { vrow[q + 256*r], 0.f };
        }
        dft16<-1>(xA, yA);
        dft16<-1>(xB, yB);
        const float ang = -PI2 * (float)q / 4096.f;
        twiddle_apply(yA, ang);
        twiddle_apply(yB, ang);
        #pragma unroll
        for (int u = 0; u < 16; ++u) {
            bufA[phys(q + 256*u)] = yA[u];
            bufB[phys(q + 256*u)] = yB[u];
        }
    }
    __syncthreads();
    // ---- forward stage 2 (stride 16 within 256-blocks)
    {
        const int blk = tid >> 4, a = tid & 15;
        const int base = 256*blk + a;
        float2 xA[16], xB[16], yA[16], yB[16];
        #pragma unroll
        for (int c = 0; c < 16; ++c) {
            xA[c] = bufA[phys(base + 16*c)];
            xB[c] = bufB[phys(base + 16*c)];
        }
        dft16<-1>(xA, yA);
        dft16<-1>(xB, yB);
        const float ang = -PI2 * (float)a / 256.f;
        twiddle_apply(yA, ang);
        twiddle_apply(yB, ang);
        #pragma unroll
        for (int c = 0; c < 16; ++c) {
            bufA[phys(base + 16*c)] = yA[c];
            bufB[phys(base + 16*c)] = yB[c];
        }
    }
    __syncthreads();
    // ---- forward stage 3 (contiguous 16)
    {
        const int blk = tid >> 4, c = tid & 15;
        const int base = 256*blk + 16*c;
        float2 xA[16], xB[16], yA[16], yB[16];
        #pragma unroll
        for (int a2 = 0; a2 < 16; ++a2) {
            xA[a2] = bufA[phys(base + a2)];
            xB[a2] = bufB[phys(base + a2)];
        }
        dft16<-1>(xA, yA);
        dft16<-1>(xB, yB);
        #pragma unroll
        for (int d = 0; d < 16; ++d) {
            bufA[phys(base + d)] = yA[d];
            bufB[phys(base + d)] = yB[d];
        }
    }
    __syncthreads();
    // ---- pointwise: F = Q * conj(K) * V, in digit-reversed positions
    #pragma unroll
    for (int it = 0; it < 16; ++it) {
        const int p  = tid + it * 256;
        const int j  = ((p & 15) << 8) | (p & 0xF0) | (p >> 8);
        const int jn = (FFT_N - j) & (FFT_N - 1);
        const int pn = ((jn & 15) << 8) | (jn & 0xF0) | (jn >> 8);
        const float2 Zj = bufA[phys(p)];
        const float2 Zn = bufA[phys(pn)];
        const float2 Q = { 0.5f*(Zj.x + Zn.x), 0.5f*(Zj.y - Zn.y) };
        const float2 K = { 0.5f*(Zj.y + Zn.y), -0.5f*(Zj.x - Zn.x) };
        const float2 G = { Q.x*K.x + Q.y*K.y, Q.y*K.x - Q.x*K.y };
        const float2 V = bufB[phys(p)];
        bufB[phys(p)] = { G.x*V.x - G.y*V.y, G.x*V.y + G.y*V.x };
    }
    __syncthreads();
    // ---- inverse stage A (contiguous 16)
    {
        const int blk = tid >> 4, c = tid & 15;
        const int base = 256*blk + 16*c;
        float2 x[16], y[16];
        #pragma unroll
        for (int d = 0; d < 16; ++d) x[d] = bufB[phys(base + d)];
        dft16<1>(x, y);
        #pragma unroll
        for (int p0 = 0; p0 < 16; ++p0) bufB[phys(base + p0)] = y[p0];
    }
    __syncthreads();
    // ---- inverse stage B (stride 16), input twiddle W_256^{+p0*c}
    {
        const int blk = tid >> 4, p0 = tid & 15;
        const int base = 256*blk + p0;
        float2 x[16], y[16];
        #pragma unroll
        for (int c = 0; c < 16; ++c) x[c] = bufB[phys(base + 16*c)];
        twiddle_apply(x, PI2 * (float)p0 / 256.f);
        dft16<1>(x, y);
        #pragma unroll
        for (int p1 = 0; p1 < 16; ++p1) bufB[phys(base + 16*p1)] = y[p1];
    }
    __syncthreads();
    // ---- inverse stage C (stride 256), twiddle W_4096^{+qq*t}, store global
    {
        const int qq = tid;
        float2 x[16], y[16];
        #pragma unroll
        for (int t = 0; t < 16; ++t) x[t] = bufB[phys(qq + 256*t)];
        twiddle_apply(x, PI2 * (float)qq / 4096.f);
        dft16<1>(x, y);
        const float scale = 0.125f / 4096.f;   // 1/sqrt(64) * 1/N
        #pragma unroll
        for (int p2 = 0; p2 < 16; ++p2)
            orow[qq + 256*p2] = y[p2].x * scale;
    }
}

// ---------------------------------------------------------------------------
// Transpose + split (UNCHANGED, validated r4)
// ---------------------------------------------------------------------------
__global__ __launch_bounds__(256) void transpose_split_kernel(
    const float* __restrict__ ot, ushort* __restrict__ oth,
    ushort* __restrict__ otl)
{
    __shared__ float tile[64][65];
    const int tid = threadIdx.x;
    const int m0  = blockIdx.x * 64;
    const int n0  = blockIdx.y * 64;
    const int r   = tid >> 4;
    const int c   = tid & 15;

    #pragma unroll
    for (int rr = 0; rr < 4; ++rr) {
        const int nl = r + rr * 16;
        float4 v = *(const float4*)(ot + (size_t)(n0 + nl) * M_TOTAL + m0 + c * 4);
        tile[nl][c * 4 + 0] = v.x; tile[nl][c * 4 + 1] = v.y;
        tile[nl][c * 4 + 2] = v.z; tile[nl][c * 4 + 3] = v.w;
    }
    __syncthreads();
    #pragma unroll
    for (int rr = 0; rr < 4; ++rr) {
        const int ml = r + rr * 16;
        ushort4 h, l;
        split1(tile[c * 4 + 0][ml], h.x, l.x);
        split1(tile[c * 4 + 1][ml], h.y, l.y);
        split1(tile[c * 4 + 2][ml], h.z, l.z);
        split1(tile[c * 4 + 3][ml], h.w, l.w);
        *(ushort4*)(oth + (size_t)(m0 + ml) * HIDDEN + n0 + c * 4) = h;
        *(ushort4*)(otl + (size_t)(m0 + ml) * HIDDEN + n0 + c * 4) = l;
    }
}

// ---------------------------------------------------------------------------
// GEMM C (MFMA, UNCHANGED, validated r4)
// ---------------------------------------------------------------------------
__global__ __launch_bounds__(256) void gemm_out_mfma(
    const ushort* __restrict__ oth, const ushort* __restrict__ otl,
    const float* __restrict__ Wo, const float* __restrict__ bo,
    float* __restrict__ out)
{
    __shared__ ushort Ah[128][32], Al[128][32];
    __shared__ ushort Bh[128][32], Bl[128][32];

    const int tid  = threadIdx.x;
    const int lane = tid & 63;
    const int w    = tid >> 6;
    const int m0   = blockIdx.x * 128;
    const int n0   = blockIdx.y * 128;

    const int fr = lane & 15;
    const int fc = lane >> 4;
    const int cc = (fc ^ (fr & 3)) * 8;

    f32x4 acc[2][8];
    #pragma unroll
    for (int i = 0; i < 2; ++i)
        #pragma unroll
        for (int j = 0; j < 8; ++j)
            acc[i][j] = (f32x4){0.f, 0.f, 0.f, 0.f};

    for (int ks = 0; ks < HIDDEN / 32; ++ks) {
        const int k0 = ks * 32;
        __syncthreads();
        #pragma unroll
        for (int t = 0; t < 2; ++t) {
            const int s   = tid + t * 256;
            const int row = s >> 2;
            const int ch  = s & 3;
            const int cs  = (ch ^ (row & 3)) * 8;
            {
                const size_t g = (size_t)(m0 + row) * HIDDEN + k0 + ch * 8;
                *(s16x8*)&Ah[row][cs] = *(const s16x8*)(oth + g);
                *(s16x8*)&Al[row][cs] = *(const s16x8*)(otl + g);
            }
            {
                const float* g = Wo + (size_t)(n0 + row) * HIDDEN + k0 + ch * 8;
                float4 v0 = *(const float4*)g;
                float4 v1 = *(const float4*)(g + 4);
                const float vv[8] = {v0.x, v0.y, v0.z, v0.w, v1.x, v1.y, v1.z, v1.w};
                s16x8 hv, lv;
                #pragma unroll
                for (int e = 0; e < 8; ++e) {
                    ushort h, l; split1(vv[e], h, l);
                    hv[e] = (short)h; lv[e] = (short)l;
                }
                *(s16x8*)&Bh[row][cs] = hv;
                *(s16x8*)&Bl[row][cs] = lv;
            }
        }
        __syncthreads();
        s16x8 a_h[2], a_l[2];
        #pragma unroll
        for (int i = 0; i < 2; ++i) {
            const int R = w * 32 + i * 16 + fr;
            a_h[i] = *(const s16x8*)&Ah[R][cc];
            a_l[i] = *(const s16x8*)&Al[R][cc];
        }
        #pragma unroll
        for (int j = 0; j < 8; ++j) {
            const int R = j * 16 + fr;
            const s16x8 b_h = *(const s16x8*)&Bh[R][cc];
            const s16x8 b_l = *(const s16x8*)&Bl[R][cc];
            #pragma unroll
            for (int i = 0; i < 2; ++i) {
                acc[i][j] = __builtin_amdgcn_mfma_f32_16x16x32_bf16(a_h[i], b_h, acc[i][j], 0, 0, 0);
                acc[i][j] = __builtin_amdgcn_mfma_f32_16x16x32_bf16(a_h[i], b_l, acc[i][j], 0, 0, 0);
                acc[i][j] = __builtin_amdgcn_mfma_f32_16x16x32_bf16(a_l[i], b_h, acc[i][j], 0, 0, 0);
            }
        }
    }

    const int rq = lane >> 4;
    float bo_v[8];
    #pragma unroll
    for (int j = 0; j < 8; ++j) bo_v[j] = bo[n0 + j * 16 + fr];
    #pragma unroll
    for (int i = 0; i < 2; ++i) {
        #pragma unroll
        for (int r = 0; r < 4; ++r) {
            const int m = m0 + w * 32 + i * 16 + rq * 4 + r;
            float* dst = out + (size_t)m * HIDDEN + n0;
            #pragma unroll
            for (int j = 0; j < 8; ++j)
                dst[j * 16 + fr] = acc[i][j][r] + bo_v[j];
        }
    }
}

// ---------------------------------------------------------------------------
extern "C" void kernel_launch(void* const* d_in, const int* in_sizes, int n_in,
                              void* d_out, int out_size, void* d_ws, size_t ws_size,
                              hipStream_t stream)
{
    const float* x  = (const float*)d_in[0];
    const float* Wq = (const float*)d_in[1];
    const float* bq = (const float*)d_in[2];
    const float* Wk = (const float*)d_in[3];
    const float* bk = (const float*)d_in[4];
    const float* Wv = (const float*)d_in[5];
    const float* bv = (const float*)d_in[6];
    const float* Wo = (const float*)d_in[7];
    const float* bo = (const float*)d_in[8];
    float* out = (float*)d_out;

    const size_t plane = (size_t)HIDDEN * M_TOTAL;
    float* qt = (float*)d_ws;
    float* kt = qt + plane;
    float* vt = qt + 2 * plane;
    float* ot = qt;                    // FFT output aliases q plane
    ushort* oth = (ushort*)kt;         // transposed bf16 hi plane
    ushort* otl = (ushort*)vt;         // lo plane

    gemm_qkv_mfma<<<dim3(M_TOTAL / 128, 24), 256, 0, stream>>>(
        x, Wq, Wk, Wv, bq, bk, bv, qt);

    fft_attn_kernel<<<dim3(HIDDEN * BATCH), 256, 0, stream>>>(qt, kt, vt, ot);

    transpose_split_kernel<<<dim3(M_TOTAL / 64, HIDDEN / 64), 256, 0, stream>>>(
        ot, oth, otl);

    gemm_out_mfma<<<dim3(M_TOTAL / 128, HIDDEN / 128), 256, 0, stream>>>(
        oth, otl, Wo, bo, out);
}